// Round 15
// baseline (345.191 us; speedup 1.0000x reference)
//
#include <hip/hip_runtime.h>
#include <math.h>

#define NB 512
#define NL 336
#define NC 321
#define NS 28
#define NW 12
#define NH 25
#define NP 8
#define NG 100
#define NT (NS + NP - 1)  // 35 cell steps
#define BSL 32            // batches per wave = 2 independent 16-col tiles
#define WPB 4             // independent waves per 256-thread block
#define NCHK 4            // L-chunks for stage 1 (7 segments each)
#define LOG2E 1.44269504088896340736f
#define N2LOG2E -2.88539008177792681472f

typedef __attribute__((ext_vector_type(8))) _Float16 f16x8;
typedef __attribute__((ext_vector_type(4))) float f32x4;

union F8 { f16x8 v; _Float16 h[8]; };

// q==3 lane carries the extra K-slots: k25=xt, k26=1.0 (A=bias row), k27..31=0
__device__ __forceinline__ void set_q3f(F8& b, bool q3, float xt) {
    b.h[1] = q3 ? (_Float16)xt : b.h[1];
    b.h[2] = q3 ? (_Float16)1.0f : b.h[2];
    b.h[3] = q3 ? (_Float16)0.0f : b.h[3];
    b.h[4] = q3 ? (_Float16)0.0f : b.h[4];
    b.h[5] = q3 ? (_Float16)0.0f : b.h[5];
    b.h[6] = q3 ? (_Float16)0.0f : b.h[6];
    b.h[7] = q3 ? (_Float16)0.0f : b.h[7];
}

// ---------------- Stage 1a: raw segment dots + partial sums -----------------
extern "C" __global__ __launch_bounds__(384)
void k_seg_part(const float* __restrict__ x, const float* __restrict__ seg,
                float* __restrict__ seg_raw, float* __restrict__ psum) {
    const int b = blockIdx.x;
    const int ch = blockIdx.y;
    const int c = threadIdx.x;
    if (c >= NC) return;
    float sw[NW];
#pragma unroll
    for (int w = 0; w < NW; ++w) sw[w] = seg[c * NW + w];
    float acc[7];
    float s0 = 0.0f, s1 = 0.0f, s2 = 0.0f, s3 = 0.0f;
    const float* xb = x + ((size_t)b * NL + ch * 84) * NC + c;
#pragma unroll
    for (int i = 0; i < 7; ++i) {
        float a = 0.0f;
        float t0 = 0.0f, t1 = 0.0f, t2 = 0.0f, t3 = 0.0f;
#pragma unroll
        for (int w = 0; w < NW; w += 4) {
            const float v0 = xb[(i * NW + w) * NC];
            const float v1 = xb[(i * NW + w + 1) * NC];
            const float v2 = xb[(i * NW + w + 2) * NC];
            const float v3 = xb[(i * NW + w + 3) * NC];
            t0 += v0; t1 += v1; t2 += v2; t3 += v3;
            a = fmaf(v0, sw[w], a);
            a = fmaf(v1, sw[w + 1], a);
            a = fmaf(v2, sw[w + 2], a);
            a = fmaf(v3, sw[w + 3], a);
        }
        s0 += t0; s1 += t1; s2 += t2; s3 += t3;
        acc[i] = a;
    }
    psum[((size_t)ch * NB + b) * NC + c] = (s0 + s1) + (s2 + s3);
#pragma unroll
    for (int i = 0; i < 7; ++i) {
        const int s = ch * 7 + i;
        seg_raw[((size_t)s * NC + c) * NB + b] = acc[i];
    }
}

// ---------------- Stage 1b: reduce partial sums to means --------------------
extern "C" __global__ __launch_bounds__(384)
void k_mean(const float* __restrict__ psum, float* __restrict__ meanw,
            float* __restrict__ meanT) {
    const int b = blockIdx.x;
    const int c = threadIdx.x;
    if (c >= NC) return;
    float s = 0.0f;
#pragma unroll
    for (int ch = 0; ch < NCHK; ++ch)
        s += psum[((size_t)ch * NB + b) * NC + c];
    const float mean = s * (1.0f / (float)NL);
    meanw[b * NC + c] = mean;
    meanT[(size_t)c * NB + b] = mean;
}

// ---------------- Stage 2: f16-MFMA LSTM, zero-LDS, 2 chains/wave -----------
// Each wave owns (channel, 32 batches) as TWO independent 16-col tiles:
// doubles in-wave ILP (two MFMA->exp2->rcp chains interleave) to cover the
// ~35% latency stall seen at 1 tile/wave (R14). hw exp2/rcp on trans pipe
// (R13: VALU-Newton rcp regresses). Mean correction folded into xt loads.
extern "C" __global__ __launch_bounds__(256, 4)
void k_lstm(const float* __restrict__ seg_raw, const float* __restrict__ W_ih,
            const float* __restrict__ W_hh, const float* __restrict__ b_ih,
            const float* __restrict__ b_hh, const float* __restrict__ Wp,
            const float* __restrict__ bp, const float* __restrict__ seg,
            const float* __restrict__ meanT, float* __restrict__ preds) {
    const int c = blockIdx.x;
    const int wv = threadIdx.x >> 6;
    const int lane = threadIdx.x & 63;
    const int b0 = (blockIdx.y * WPB + wv) * BSL;
    const int bb = lane & 15;         // column (batch) / A-row
    const int q  = lane >> 4;         // k-chunk / C row-quad
    const bool q3 = (q == 3);

    // per-wave constants: ssum and per-tile means
    float ssc = 0.0f;
#pragma unroll
    for (int w = 0; w < NW; ++w) ssc += seg[c * NW + w];
    const float mc0 = meanT[(size_t)c * NB + b0 + bb] * ssc;
    const float mc1 = meanT[(size_t)c * NB + b0 + 16 + bb] * ssc;

    // ---- hoisted A-fragments from global (one-time, L2/L3-resident) ----
    const int qq = bb >> 2, rr = bb & 3;
    const float srow = (rr == 2) ? 2.88539008177792681472f : LOG2E;
    const float* __restrict__ whh = W_hh + (size_t)c * NG * NH;
    const float* __restrict__ wxp = W_ih + (size_t)c * NG;
    const float* __restrict__ bip = b_ih + (size_t)c * NG;
    const float* __restrict__ bhp = b_hh + (size_t)c * NG;
    F8 afr[8];
#pragma unroll 1
    for (int mg = 0; mg < 8; ++mg) {
        const int jj = qq * 8 + mg;
        const int grow = rr * NH + jj;
        F8 f0;
#pragma unroll
        for (int e = 0; e < 8; ++e) {
            const int k = q * 8 + e;
            float v0 = 0.0f;
            if (jj < NH) {
                if (k < NH)         v0 = whh[grow * NH + k] * srow;
                else if (k == 25)   v0 = wxp[grow] * srow;
                else if (k == 26)   v0 = (bip[grow] + bhp[grow]) * srow;
            }
            f0.h[e] = (_Float16)v0;
        }
        afr[mg] = f0;
    }

    float wpl[8];
#pragma unroll
    for (int mg = 0; mg < 8; ++mg) {
        const int j = q * 8 + mg;
        wpl[mg] = (j < NH) ? Wp[(size_t)c * NH + j] : 0.0f;
    }
    const float bpc = bp[c];

    // ---- initial B-fragments: h = 0, xt = seg_in[s=0] per tile ----
    F8 ph0, ph1;
    {
        const float x0 = seg_raw[(size_t)c * NB + b0 + bb] - mc0;
        const float x1 = seg_raw[(size_t)c * NB + b0 + 16 + bb] - mc1;
#pragma unroll
        for (int e = 0; e < 8; ++e) { ph0.h[e] = (_Float16)0.0f; ph1.h[e] = (_Float16)0.0f; }
        set_q3f(ph0, q3, x0);
        set_q3f(ph1, q3, x1);
    }

    float cst0[8], cst1[8];
#pragma unroll
    for (int mg = 0; mg < 8; ++mg) { cst0[mg] = 0.0f; cst1[mg] = 0.0f; }

    // ---- recurrence: two independent register-dataflow chains ----
#pragma unroll 1
    for (int t = 0; t < NT; ++t) {
        const bool enc_next = (t + 1 < NS);
        const bool do_proj = (t >= NS - 1);
        const bool have_next = (t + 1 < NT);

        // prefetch next encoder inputs early (L2/L3-resident), mean-corrected
        float xn0 = 0.0f, xn1 = 0.0f;
        if (enc_next) {
            const float* p = seg_raw + ((size_t)(t + 1) * NC + c) * NB + b0;
            xn0 = p[bb] - mc0;
            xn1 = p[16 + bb] - mc1;
        }

        // phase 1: 16 independent MFMAs (both tiles)
        f32x4 av0[8], av1[8];
#pragma unroll
        for (int mg = 0; mg < 8; ++mg) {
            f32x4 z = {0.0f, 0.0f, 0.0f, 0.0f};
            av0[mg] = __builtin_amdgcn_mfma_f32_16x16x32_f16(afr[mg].v, ph0.v, z, 0, 0, 0);
            av1[mg] = __builtin_amdgcn_mfma_f32_16x16x32_f16(afr[mg].v, ph1.v, z, 0, 0, 0);
        }

        // phases 2+3 per tile, mg-interleaved by the scheduler (indep chains)
        float hnv0[8], hnv1[8];
        float pp0 = 0.0f, pp1 = 0.0f;
#pragma unroll
        for (int mg = 0; mg < 8; ++mg) {
            {
                const float ei = __builtin_amdgcn_exp2f(-av0[mg][0]);
                const float ef = __builtin_amdgcn_exp2f(-av0[mg][1]);
                const float eg = __builtin_amdgcn_exp2f(-av0[mg][2]);
                const float eo = __builtin_amdgcn_exp2f(-av0[mg][3]);
                const float p1f = 1.0f + ef;
                const float pig = (1.0f + ei) * (1.0f + eg);
                const float num = fmaf(cst0[mg], pig, (1.0f - eg) * p1f);
                const float cn  = num * __builtin_amdgcn_rcpf(p1f * pig);
                const float et  = __builtin_amdgcn_exp2f(cn * N2LOG2E);
                const float hn  = (1.0f - et) *
                                  __builtin_amdgcn_rcpf((1.0f + eo) * (1.0f + et));
                cst0[mg] = cn;
                hnv0[mg] = hn;
                if (do_proj) pp0 = fmaf(hn, wpl[mg], pp0);
            }
            {
                const float ei = __builtin_amdgcn_exp2f(-av1[mg][0]);
                const float ef = __builtin_amdgcn_exp2f(-av1[mg][1]);
                const float eg = __builtin_amdgcn_exp2f(-av1[mg][2]);
                const float eo = __builtin_amdgcn_exp2f(-av1[mg][3]);
                const float p1f = 1.0f + ef;
                const float pig = (1.0f + ei) * (1.0f + eg);
                const float num = fmaf(cst1[mg], pig, (1.0f - eg) * p1f);
                const float cn  = num * __builtin_amdgcn_rcpf(p1f * pig);
                const float et  = __builtin_amdgcn_exp2f(cn * N2LOG2E);
                const float hn  = (1.0f - et) *
                                  __builtin_amdgcn_rcpf((1.0f + eo) * (1.0f + et));
                cst1[mg] = cn;
                hnv1[mg] = hn;
                if (do_proj) pp1 = fmaf(hn, wpl[mg], pp1);
            }
        }

        float ov0 = 0.0f, ov1 = 0.0f;
        if (do_proj) {
            pp0 += __shfl_xor(pp0, 16);
            pp0 += __shfl_xor(pp0, 32);
            pp1 += __shfl_xor(pp1, 16);
            pp1 += __shfl_xor(pp1, 32);
            ov0 = pp0 + bpc;
            ov1 = pp1 + bpc;
            if (q == 0) {
                float* pd = preds + ((size_t)c * NP + (t - (NS - 1))) * NB + b0;
                pd[bb] = ov0;
                pd[16 + bb] = ov1;
            }
        }

        if (have_next) {
#pragma unroll
            for (int e = 0; e < 8; ++e) {
                ph0.h[e] = (_Float16)hnv0[e];
                ph1.h[e] = (_Float16)hnv1[e];
            }
            set_q3f(ph0, q3, enc_next ? xn0 : ov0);
            set_q3f(ph1, q3, enc_next ? xn1 : ov1);
        }
    }
}

// ---------------- Stage 3: expand predictions to output ---------------------
extern "C" __global__ __launch_bounds__(384)
void k_out(const float* __restrict__ preds, const float* __restrict__ seg,
           const float* __restrict__ meanw, float* __restrict__ out) {
    const int b = blockIdx.x;
    const int p = blockIdx.y;
    const int c = threadIdx.x;
    if (c >= NC) return;
    const float pv = preds[((size_t)c * NP + p) * NB + b];
    const float mean = meanw[b * NC + c];
    float* ob = out + ((size_t)b * (NP * NW) + p * NW) * NC + c;
#pragma unroll
    for (int w = 0; w < NW; ++w)
        ob[w * NC] = fmaf(pv, seg[c * NW + w], mean);
}

extern "C" void kernel_launch(void* const* d_in, const int* in_sizes, int n_in,
                              void* d_out, int out_size, void* d_ws, size_t ws_size,
                              hipStream_t stream) {
    const float* x    = (const float*)d_in[0];
    const float* seg  = (const float*)d_in[1];
    const float* W_ih = (const float*)d_in[2];
    const float* W_hh = (const float*)d_in[3];
    const float* b_ih = (const float*)d_in[4];
    const float* b_hh = (const float*)d_in[5];
    const float* Wp   = (const float*)d_in[6];
    const float* bp   = (const float*)d_in[7];
    float* out = (float*)d_out;

    float* seg_raw = (float*)d_ws;                       // 28*321*512
    float* psum    = seg_raw + (size_t)NS * NC * NB;     // 4*512*321
    float* meanw   = psum + (size_t)NCHK * NB * NC;      // 512*321
    float* meanT   = meanw + (size_t)NB * NC;            // 321*512
    float* preds   = meanT + (size_t)NC * NB;            // 321*8*512

    k_seg_part<<<dim3(NB, NCHK), 384, 0, stream>>>(x, seg, seg_raw, psum);
    k_mean<<<NB, 384, 0, stream>>>(psum, meanw, meanT);
    k_lstm<<<dim3(NC, NB / (BSL * WPB)), 256, 0, stream>>>(
        seg_raw, W_ih, W_hh, b_ih, b_hh, Wp, bp, seg, meanT, preds);
    k_out<<<dim3(NB, NP), 384, 0, stream>>>(preds, seg, meanw, out);
}